// Round 1
// baseline (9159.145 us; speedup 1.0000x reference)
//
#include <hip/hip_runtime.h>
#include <hip/hip_bf16.h>

// Elman RNN: B=256, T=512, H=1024, O=256 (all fp32 in/out).
// Strategy: 256 WGs = 16 batch-blocks x 16 col-blocks. Each WG keeps its
// [1024 x 64] W_ih slice as bf16 MFMA B-fragments in registers; h state lives
// in a double-buffered bf16 array in d_ws; producer/consumer flags per batch
// group (16 WGs) provide the only inter-WG sync (no grid barrier needed since
// the recurrence is independent per batch row).

#define Bsz 256
#define Tn  512
#define Hn  1024
#define On  256

typedef __attribute__((ext_vector_type(8))) short bf16x8;  // 8 bf16 = 4 VGPRs
typedef __attribute__((ext_vector_type(4))) float f32x4;

__device__ __forceinline__ short f2bf(float f) {
    union { float f; unsigned u; } v; v.f = f;
    unsigned r = v.u + 0x7FFFu + ((v.u >> 16) & 1u);   // RNE
    return (short)(r >> 16);
}

__global__ __launch_bounds__(256, 1) void rnn_kernel(
    const float* __restrict__ x,      // [B][T]
    const float* __restrict__ W_ih,   // [1+H][H]
    const float* __restrict__ b_ih,   // [H]
    const float* __restrict__ W_ho,   // [H][O]
    const float* __restrict__ b_ho,   // [O]
    float* __restrict__ out,          // [B][O]
    short* __restrict__ hbuf,         // ws: 2 * B * H bf16 (as raw shorts)
    int*   __restrict__ flags)        // ws: [16][16] int (poison 0xAA.. < 0 ok)
{
    const int tid  = threadIdx.x;
    const int lane = tid & 63;
    const int w    = tid >> 6;      // wave 0..3 -> 16-col sub-block
    const int q    = lane >> 4;     // 0..3  (k-group for A/B frags, row-group for C/D)
    const int n    = lane & 15;     // A row m / B col n / D col

    // member = blockIdx/16, group = blockIdx%16 -> group members share an XCD
    // under round-robin dispatch (perf heuristic only).
    const int i = blockIdx.x & 15;  // batch block: rows 16i..16i+15
    const int j = blockIdx.x >> 4;  // col block:   cols 64j..64j+63

    const int col  = j * 64 + w * 16 + n;   // H column owned by this lane (B operand)
    const int row0 = i * 16;

    __shared__ float x_lds[16][Tn];   // 32 KB: this block's x rows, fp32
    __shared__ float red[4][16][16];  // 4 KB: cross-wave reduce for output GEMM

    // Stage x rows (coalesced).
    for (int idx = tid; idx < 16 * Tn; idx += 256) {
        int r = idx >> 9, t = idx & (Tn - 1);
        x_lds[r][t] = x[(row0 + r) * Tn + t];
    }

    // W_ih slice -> bf16 B-fragments in registers.
    // B frag layout (16x16x32): lane (k/8)*16+n holds B[k][n], 8 consecutive k.
    bf16x8 bfrag[32];
#pragma unroll
    for (int kk = 0; kk < 32; ++kk) {
#pragma unroll
        for (int e = 0; e < 8; ++e) {
            int k = kk * 32 + q * 8 + e;
            bfrag[kk][e] = f2bf(W_ih[(1 + k) * Hn + col]);
        }
    }
    const float w0c  = W_ih[col];   // W_ih[0][col] (x weight), fp32
    const float bias = b_ih[col];

    __syncthreads();

    short* h0 = hbuf;
    short* h1 = hbuf + Bsz * Hn;
    int* myflags = flags + i * 16;

    for (int t = 0; t < Tn; ++t) {
        f32x4 acc = {bias, bias, bias, bias};
        // x-term in fp32 (exact): D row = 4q+r, col = n.
#pragma unroll
        for (int r = 0; r < 4; ++r)
            acc[r] += x_lds[q * 4 + r][t] * w0c;

        if (t > 0) {
            // Wait for all 16 group members to publish h_t.
            for (;;) {
                int v = 0x7fffffff;
                if (lane < 16)
                    v = __hip_atomic_load(&myflags[lane], __ATOMIC_RELAXED,
                                          __HIP_MEMORY_SCOPE_AGENT);
                if (__all(v >= t)) break;
                __builtin_amdgcn_s_sleep(1);
            }
            __builtin_amdgcn_fence(__ATOMIC_ACQUIRE, "agent");

            const short* hsrc = (t & 1) ? h1 : h0;
            // A frag layout: lane (k/8)*16+m holds A[m][k], 8 consecutive k.
            const short* arow = hsrc + (row0 + n) * Hn + q * 8;
#pragma unroll
            for (int kk = 0; kk < 32; ++kk) {
                bf16x8 afrag = *(const bf16x8*)(arow + kk * 32);
                acc = __builtin_amdgcn_mfma_f32_16x16x32_bf16(afrag, bfrag[kk],
                                                              acc, 0, 0, 0);
            }
        }

        // h_{t+1} = tanh(acc); store bf16. D: row = 4q+r, col = n (verified map).
        short* hdst = ((t + 1) & 1) ? h1 : h0;
#pragma unroll
        for (int r = 0; r < 4; ++r) {
            float hv = tanhf(acc[r]);
            hdst[(row0 + q * 4 + r) * Hn + col] = f2bf(hv);
        }

        __syncthreads();  // drains vmcnt: all waves' stores are in L2
        if (tid == 0) {
            __builtin_amdgcn_fence(__ATOMIC_RELEASE, "agent");  // wb to coherence pt
            __hip_atomic_store(&flags[i * 16 + j], t + 1, __ATOMIC_RELAXED,
                               __HIP_MEMORY_SCOPE_AGENT);
        }
    }

    // Wait for group to finish h_T.
    for (;;) {
        int v = 0x7fffffff;
        if (lane < 16)
            v = __hip_atomic_load(&myflags[lane], __ATOMIC_RELAXED,
                                  __HIP_MEMORY_SCOPE_AGENT);
        if (__all(v >= Tn)) break;
        __builtin_amdgcn_s_sleep(1);
    }
    __builtin_amdgcn_fence(__ATOMIC_ACQUIRE, "agent");

    // out[16i..+16][16j..+16] = h_T @ W_ho + b_ho ; K=1024 split over 4 waves.
    const short* hT = h0;  // T even -> h_T in buf 0
    f32x4 acc = {0.f, 0.f, 0.f, 0.f};
    const short* arow = hT + (row0 + n) * Hn + w * 256 + q * 8;
    const float* wcol = W_ho + (w * 256 + q * 8) * On + j * 16 + n;
#pragma unroll
    for (int kk = 0; kk < 8; ++kk) {
        bf16x8 afrag = *(const bf16x8*)(arow + kk * 32);
        bf16x8 bfr;
#pragma unroll
        for (int e = 0; e < 8; ++e)
            bfr[e] = f2bf(wcol[(kk * 32 + e) * On]);
        acc = __builtin_amdgcn_mfma_f32_16x16x32_bf16(afrag, bfr, acc, 0, 0, 0);
    }
#pragma unroll
    for (int r = 0; r < 4; ++r)
        red[w][q * 4 + r][n] = acc[r];
    __syncthreads();

    {
        int r = tid >> 4, c = tid & 15;
        float s = red[0][r][c] + red[1][r][c] + red[2][r][c] + red[3][r][c]
                + b_ho[j * 16 + c];
        out[(row0 + r) * On + j * 16 + c] = s;
    }
}

extern "C" void kernel_launch(void* const* d_in, const int* in_sizes, int n_in,
                              void* d_out, int out_size, void* d_ws, size_t ws_size,
                              hipStream_t stream) {
    const float* x    = (const float*)d_in[0];
    const float* W_ih = (const float*)d_in[1];
    const float* b_ih = (const float*)d_in[2];
    const float* W_ho = (const float*)d_in[3];
    const float* b_ho = (const float*)d_in[4];
    float* out = (float*)d_out;

    size_t need = (size_t)2 * Bsz * Hn * sizeof(short) + 16 * 16 * sizeof(int);
    if (ws_size < need) return;  // fail loudly via absmax rather than corrupt

    short* hbuf  = (short*)d_ws;
    int*   flags = (int*)((char*)d_ws + (size_t)2 * Bsz * Hn * sizeof(short));

    rnn_kernel<<<256, 256, 0, stream>>>(x, W_ih, b_ih, W_ho, b_ho, out,
                                        hbuf, flags);
}

// Round 2
// 2271.837 us; speedup vs baseline: 4.0316x; 4.0316x over previous
//
#include <hip/hip_runtime.h>
#include <hip/hip_bf16.h>

// Elman RNN: B=256, T=512, H=1024, O=256 (fp32 in/out), MI355X gfx950.
// 256 WGs = 16 batch-groups x 16 col-members. W_ih slice (1024x64) lives in
// registers as bf16 A-fragments (A = W^T so the MFMA D-tile is [col][row],
// making each lane's 4 outputs contiguous -> one 8B h-store per lane).
// h state: double-buffered bf16 in d_ws, kept coherent via sc0|sc1
// write-through stores + sc0|sc1 bypass loads at the MALL (no buffer_wbl2 /
// buffer_inv agent fences). Per-group flags: relaxed agent atomics.
// Each step the WG stages its group's 32KB h-slice into LDS once
// (XOR-swizzled 16B granules, conflict-free b128 read/write).

#define Bsz 256
#define Tn  512
#define Hn  1024
#define On  256

typedef __attribute__((ext_vector_type(8))) short bf16x8;  // 8 bf16 = 4 VGPR
typedef __attribute__((ext_vector_type(4))) float f32x4;
typedef __attribute__((ext_vector_type(4))) int   i32x4;
typedef __attribute__((ext_vector_type(2))) int   i32x2;

__device__ __forceinline__ short f2bf(float f) {
    union { float f; unsigned u; } v; v.f = f;
    unsigned r = v.u + 0x7FFFu + ((v.u >> 16) & 1u);   // RNE
    return (short)(r >> 16);
}

__device__ __forceinline__ bf16x8 as_bf16x8(i32x4 v) {
    union { i32x4 i; bf16x8 b; } u; u.i = v; return u.b;
}

// Pull this group's 16x1024 bf16 h-slice from the MALL into LDS.
// Thread (r = tid&15, c = tid>>4) copies row r, granules g = c*8 .. c*8+7
// (granule = 8 bf16 = 16B), stored at swizzled index g ^ (r&7).
// sc0 sc1: bypass L1+L2 so we read the coherence point (safe cross-XCD).
__device__ __forceinline__ void stage_h(const short* __restrict__ hsrc,
                                        short* __restrict__ htile,
                                        int row0, int tid) {
    const int r = tid & 15;
    const int c = tid >> 4;
    const short* gp = hsrc + (row0 + r) * Hn + c * 64;
    i32x4 t0, t1, t2, t3, t4, t5, t6, t7;
    asm volatile(
        "global_load_dwordx4 %0, %8, off sc0 sc1\n\t"
        "global_load_dwordx4 %1, %8, off offset:16 sc0 sc1\n\t"
        "global_load_dwordx4 %2, %8, off offset:32 sc0 sc1\n\t"
        "global_load_dwordx4 %3, %8, off offset:48 sc0 sc1\n\t"
        "global_load_dwordx4 %4, %8, off offset:64 sc0 sc1\n\t"
        "global_load_dwordx4 %5, %8, off offset:80 sc0 sc1\n\t"
        "global_load_dwordx4 %6, %8, off offset:96 sc0 sc1\n\t"
        "global_load_dwordx4 %7, %8, off offset:112 sc0 sc1\n\t"
        "s_waitcnt vmcnt(0)"
        : "=&v"(t0), "=&v"(t1), "=&v"(t2), "=&v"(t3),
          "=&v"(t4), "=&v"(t5), "=&v"(t6), "=&v"(t7)
        : "v"(gp)
        : "memory");
    i32x4* lrow = (i32x4*)(htile + r * Hn);
    const int swz = r & 7, g0 = c * 8;
    lrow[(g0 + 0) ^ swz] = t0;
    lrow[(g0 + 1) ^ swz] = t1;
    lrow[(g0 + 2) ^ swz] = t2;
    lrow[(g0 + 3) ^ swz] = t3;
    lrow[(g0 + 4) ^ swz] = t4;
    lrow[(g0 + 5) ^ swz] = t5;
    lrow[(g0 + 6) ^ swz] = t6;
    lrow[(g0 + 7) ^ swz] = t7;
}

__device__ __forceinline__ void wait_group(const int* __restrict__ gflags,
                                           int lane, int t) {
    for (;;) {
        int v = 0x7fffffff;
        if (lane < 16)
            v = __hip_atomic_load(&gflags[lane], __ATOMIC_RELAXED,
                                  __HIP_MEMORY_SCOPE_AGENT);
        if (__all(v >= t)) break;
        __builtin_amdgcn_s_sleep(1);
    }
    __atomic_signal_fence(__ATOMIC_SEQ_CST);  // compiler ordering only
}

__global__ __launch_bounds__(256, 1) void rnn_kernel(
    const float* __restrict__ x,      // [B][T]
    const float* __restrict__ W_ih,   // [1+H][H]
    const float* __restrict__ b_ih,   // [H]
    const float* __restrict__ W_ho,   // [H][O]
    const float* __restrict__ b_ho,   // [O]
    float* __restrict__ out,          // [B][O]
    short* __restrict__ hbuf,         // ws: 2 * B * H bf16
    int*   __restrict__ flags)        // ws: [16][16] int (0xAA.. poison < 0)
{
    const int tid  = threadIdx.x;
    const int lane = tid & 63;
    const int w    = tid >> 6;      // wave 0..3 -> 16-col sub-block
    const int q    = lane >> 4;     // k-group (A/B), row-group (D)
    const int n    = lane & 15;     // batch row (B col / D col)

    const int i = blockIdx.x & 15;  // batch group
    const int j = blockIdx.x >> 4;  // col member
    const int colbase = j * 64 + w * 16;
    const int row0    = i * 16;

    __shared__ float x_lds[16][Tn + 1];   // +1 pad: bank-spread x reads
    __shared__ short htile[16 * Hn];      // 32KB staged h slice (swizzled)
    __shared__ float red[4][16][16];      // epilogue cross-wave reduce

    // Stage x rows.
    for (int idx = tid; idx < 16 * Tn; idx += 256) {
        int r = idx >> 9, tt = idx & (Tn - 1);
        x_lds[r][tt] = x[(row0 + r) * Tn + tt];
    }

    // A = W^T fragments: lane (q,n) holds A[m=n][k=q*8+e] = W_ih[1+k][colbase+n].
    bf16x8 wfrag[32];
#pragma unroll
    for (int kk = 0; kk < 32; ++kk) {
#pragma unroll
        for (int e = 0; e < 8; ++e) {
            int k = kk * 32 + q * 8 + e;
            wfrag[kk][e] = f2bf(W_ih[(1 + k) * Hn + colbase + n]);
        }
    }
    // Per-lane 4 output cols: colbase + 4q + r, r=0..3.
    const float4 bias4 = *(const float4*)(b_ih + colbase + 4 * q);
    const float4 w04   = *(const float4*)(W_ih + colbase + 4 * q);  // row 0

    __syncthreads();

    short* h0 = hbuf;
    short* h1 = hbuf + Bsz * Hn;
    int* myflags = flags + i * 16;
    const int swn = n & 7;

    for (int t = 0; t < Tn; ++t) {
        const float xv = x_lds[n][t];
        f32x4 a0 = {bias4.x + xv * w04.x, bias4.y + xv * w04.y,
                    bias4.z + xv * w04.z, bias4.w + xv * w04.w};

        if (t > 0) {
            wait_group(myflags, lane, t);
            stage_h((t & 1) ? h1 : h0, htile, row0, tid);
            __syncthreads();

            f32x4 a1 = {0.f, 0.f, 0.f, 0.f};
            f32x4 a2 = {0.f, 0.f, 0.f, 0.f};
            f32x4 a3 = {0.f, 0.f, 0.f, 0.f};
            const i32x4* lrow = (const i32x4*)(htile + n * Hn);
#pragma unroll
            for (int kk = 0; kk < 32; kk += 4) {
                bf16x8 b0 = as_bf16x8(lrow[((kk + 0) * 4 + q) ^ swn]);
                bf16x8 b1 = as_bf16x8(lrow[((kk + 1) * 4 + q) ^ swn]);
                bf16x8 b2 = as_bf16x8(lrow[((kk + 2) * 4 + q) ^ swn]);
                bf16x8 b3 = as_bf16x8(lrow[((kk + 3) * 4 + q) ^ swn]);
                a0 = __builtin_amdgcn_mfma_f32_16x16x32_bf16(wfrag[kk + 0], b0, a0, 0, 0, 0);
                a1 = __builtin_amdgcn_mfma_f32_16x16x32_bf16(wfrag[kk + 1], b1, a1, 0, 0, 0);
                a2 = __builtin_amdgcn_mfma_f32_16x16x32_bf16(wfrag[kk + 2], b2, a2, 0, 0, 0);
                a3 = __builtin_amdgcn_mfma_f32_16x16x32_bf16(wfrag[kk + 3], b3, a3, 0, 0, 0);
            }
            a0 = a0 + a1;
            a2 = a2 + a3;
            a0 = a0 + a2;
        }

        // h_{t+1}[row0+n][colbase+4q+r] = tanh(a0[r]) — 4 contiguous cols.
        short s0 = f2bf(tanhf(a0[0]));
        short s1 = f2bf(tanhf(a0[1]));
        short s2 = f2bf(tanhf(a0[2]));
        short s3 = f2bf(tanhf(a0[3]));
        i32x2 pk;
        pk[0] = (s0 & 0xffff) | ((int)s1 << 16);
        pk[1] = (s2 & 0xffff) | ((int)s3 << 16);
        short* hdst = (((t + 1) & 1) ? h1 : h0) + (row0 + n) * Hn + colbase + 4 * q;
        asm volatile("global_store_dwordx2 %0, %1, off sc0 sc1"
                     :: "v"(hdst), "v"(pk) : "memory");
        asm volatile("s_waitcnt vmcnt(0)" ::: "memory");  // drain to MALL
        __syncthreads();  // all waves drained; also protects htile reuse
        if (tid == 0)
            __hip_atomic_store(&flags[i * 16 + j], t + 1, __ATOMIC_RELAXED,
                               __HIP_MEMORY_SCOPE_AGENT);
    }

    // ---- Epilogue: out = h_T @ W_ho + b_ho (h_T in buffer 0, Tn even) ----
    wait_group(myflags, lane, Tn);
    stage_h(h0, htile, row0, tid);
    __syncthreads();

    f32x4 acc = {0.f, 0.f, 0.f, 0.f};
    {
        const i32x4* lrow = (const i32x4*)(htile + n * Hn);
        const float* wcol = W_ho + (w * 256 + q * 8) * On + j * 16 + n;
#pragma unroll
        for (int kk = 0; kk < 8; ++kk) {
            bf16x8 af = as_bf16x8(lrow[(w * 32 + kk * 4 + q) ^ swn]);
            bf16x8 bf_;
#pragma unroll
            for (int e = 0; e < 8; ++e)
                bf_[e] = f2bf(wcol[(kk * 32 + e) * On]);
            acc = __builtin_amdgcn_mfma_f32_16x16x32_bf16(af, bf_, acc, 0, 0, 0);
        }
    }
#pragma unroll
    for (int r = 0; r < 4; ++r)
        red[w][q * 4 + r][n] = acc[r];
    __syncthreads();

    {
        int r = tid >> 4, c = tid & 15;
        float s = red[0][r][c] + red[1][r][c] + red[2][r][c] + red[3][r][c]
                + b_ho[j * 16 + c];
        out[(row0 + r) * On + j * 16 + c] = s;
    }
}

extern "C" void kernel_launch(void* const* d_in, const int* in_sizes, int n_in,
                              void* d_out, int out_size, void* d_ws, size_t ws_size,
                              hipStream_t stream) {
    const float* x    = (const float*)d_in[0];
    const float* W_ih = (const float*)d_in[1];
    const float* b_ih = (const float*)d_in[2];
    const float* W_ho = (const float*)d_in[3];
    const float* b_ho = (const float*)d_in[4];
    float* out = (float*)d_out;

    size_t need = (size_t)2 * Bsz * Hn * sizeof(short) + 16 * 16 * sizeof(int);
    if (ws_size < need) return;

    short* hbuf  = (short*)d_ws;
    int*   flags = (int*)((char*)d_ws + (size_t)2 * Bsz * Hn * sizeof(short));

    rnn_kernel<<<256, 256, 0, stream>>>(x, W_ih, b_ih, W_ho, b_ho, out,
                                        hbuf, flags);
}

// Round 4
// 1504.910 us; speedup vs baseline: 6.0862x; 1.5096x over previous
//
#include <hip/hip_runtime.h>
#include <hip/hip_bf16.h>

// Elman RNN: B=256, T=512, H=1024, O=256 (fp32 in/out), MI355X gfx950.
// 256 WGs = 16 batch-groups x 16 col-members. W_ih slice (1024x64) in
// registers as bf16 A-fragments (A = W^T -> each lane's 4 outputs are 4
// contiguous h columns -> one 8B store). h state double-buffered bf16 in
// d_ws, coherent via sc0|sc1 write-through stores + sc0|sc1 bypass loads
// (no L2 flush/inv fences). Per-group flags: relaxed agent atomics.
// Round 4: stage_h coalesced (each load instr = one contiguous 1024B span,
// 8 full 128B lines) with the 13-bit signed offset limit respected via two
// base pointers (offsets 0..3072 each).

#define Bsz 256
#define Tn  512
#define Hn  1024
#define On  256

typedef __attribute__((ext_vector_type(8))) short bf16x8;  // 8 bf16 = 4 VGPR
typedef __attribute__((ext_vector_type(4))) float f32x4;
typedef __attribute__((ext_vector_type(4))) int   i32x4;
typedef __attribute__((ext_vector_type(2))) int   i32x2;

__device__ __forceinline__ short f2bf(float f) {
    union { float f; unsigned u; } v; v.f = f;
    unsigned r = v.u + 0x7FFFu + ((v.u >> 16) & 1u);   // RNE
    return (short)(r >> 16);
}

__device__ __forceinline__ bf16x8 as_bf16x8(i32x4 v) {
    union { i32x4 i; bf16x8 b; } u; u.i = v; return u.b;
}

// Pull this group's 16x1024 bf16 h-slice from the MALL into LDS.
// Coalesced: wave w, instr k -> row row0 + w*4 + (k>>1), half (k&1);
// lane i reads 16B at byte offset i*16 within a contiguous 1024B span.
// Offsets capped at 3072 (13-bit signed limit) via second base pointer.
// LDS: granule g of row r stored at 16B-index r*128 + (g ^ (r&7)) — per
// instruction a permutation of a contiguous 1024B block (conflict-free),
// matching the MFMA B-frag read swizzle.
__device__ __forceinline__ void stage_h(const short* __restrict__ hsrc,
                                        short* __restrict__ htile,
                                        int row0, int w, int lane) {
    const short* gp  = hsrc + (row0 + w * 4) * Hn + lane * 8;
    const short* gp2 = gp + 2048;  // +4096 bytes
    i32x4 t0, t1, t2, t3, t4, t5, t6, t7;
    asm volatile(
        "global_load_dwordx4 %0, %8, off sc0 sc1\n\t"
        "global_load_dwordx4 %1, %8, off offset:1024 sc0 sc1\n\t"
        "global_load_dwordx4 %2, %8, off offset:2048 sc0 sc1\n\t"
        "global_load_dwordx4 %3, %8, off offset:3072 sc0 sc1\n\t"
        "global_load_dwordx4 %4, %9, off sc0 sc1\n\t"
        "global_load_dwordx4 %5, %9, off offset:1024 sc0 sc1\n\t"
        "global_load_dwordx4 %6, %9, off offset:2048 sc0 sc1\n\t"
        "global_load_dwordx4 %7, %9, off offset:3072 sc0 sc1\n\t"
        "s_waitcnt vmcnt(0)"
        : "=&v"(t0), "=&v"(t1), "=&v"(t2), "=&v"(t3),
          "=&v"(t4), "=&v"(t5), "=&v"(t6), "=&v"(t7)
        : "v"(gp), "v"(gp2)
        : "memory");
    i32x4 tv[8] = {t0, t1, t2, t3, t4, t5, t6, t7};
#pragma unroll
    for (int k = 0; k < 8; ++k) {
        int row = w * 4 + (k >> 1);
        int g   = (k & 1) * 64 + lane;
        int idx = row * 128 + (g ^ (row & 7));
        *(i32x4*)(htile + idx * 8) = tv[k];
    }
}

__device__ __forceinline__ void wait_group(const int* __restrict__ gflags,
                                           int lane, int t) {
    for (;;) {
        int v = 0x7fffffff;
        if (lane < 16)
            v = __hip_atomic_load(&gflags[lane], __ATOMIC_RELAXED,
                                  __HIP_MEMORY_SCOPE_AGENT);
        if (__all(v >= t)) break;
        __builtin_amdgcn_s_sleep(1);
    }
    __atomic_signal_fence(__ATOMIC_SEQ_CST);  // compiler ordering only
}

__global__ __launch_bounds__(256, 1) void rnn_kernel(
    const float* __restrict__ x,      // [B][T]
    const float* __restrict__ W_ih,   // [1+H][H]
    const float* __restrict__ b_ih,   // [H]
    const float* __restrict__ W_ho,   // [H][O]
    const float* __restrict__ b_ho,   // [O]
    float* __restrict__ out,          // [B][O]
    short* __restrict__ hbuf,         // ws: 2 * B * H bf16
    int*   __restrict__ flags)        // ws: [16][16] int (0xAA.. poison < 0)
{
    const int tid  = threadIdx.x;
    const int lane = tid & 63;
    const int w    = tid >> 6;      // wave 0..3 -> 16-col sub-block
    const int q    = lane >> 4;     // k-group (A/B), row-group (D)
    const int n    = lane & 15;     // batch row (B col / D col)

    const int i = blockIdx.x & 15;  // batch group
    const int j = blockIdx.x >> 4;  // col member
    const int colbase = j * 64 + w * 16;
    const int row0    = i * 16;

    __shared__ float x_lds[16][Tn + 1];   // +1 pad: bank-spread x reads
    __shared__ short htile[16 * Hn];      // 32KB staged h slice (swizzled)
    __shared__ float red[4][16][16];      // epilogue cross-wave reduce

    // Stage x rows.
    for (int idx = tid; idx < 16 * Tn; idx += 256) {
        int r = idx >> 9, tt = idx & (Tn - 1);
        x_lds[r][tt] = x[(row0 + r) * Tn + tt];
    }

    // A = W^T fragments: lane (q,n) holds A[m=n][k=q*8+e] = W_ih[1+k][colbase+n].
    bf16x8 wfrag[32];
#pragma unroll
    for (int kk = 0; kk < 32; ++kk) {
#pragma unroll
        for (int e = 0; e < 8; ++e) {
            int k = kk * 32 + q * 8 + e;
            wfrag[kk][e] = f2bf(W_ih[(1 + k) * Hn + colbase + n]);
        }
    }
    // Per-lane 4 output cols: colbase + 4q + r, r=0..3.
    const float4 bias4 = *(const float4*)(b_ih + colbase + 4 * q);
    const float4 w04   = *(const float4*)(W_ih + colbase + 4 * q);  // row 0

    __syncthreads();

    short* h0 = hbuf;
    short* h1 = hbuf + Bsz * Hn;
    int* myflags = flags + i * 16;
    const int swn = n & 7;

    for (int t = 0; t < Tn; ++t) {
        const float xv = x_lds[n][t];
        f32x4 a0 = {bias4.x + xv * w04.x, bias4.y + xv * w04.y,
                    bias4.z + xv * w04.z, bias4.w + xv * w04.w};

        if (t > 0) {
            wait_group(myflags, lane, t);
            stage_h((t & 1) ? h1 : h0, htile, row0, w, lane);
            __syncthreads();

            f32x4 a1 = {0.f, 0.f, 0.f, 0.f};
            f32x4 a2 = {0.f, 0.f, 0.f, 0.f};
            f32x4 a3 = {0.f, 0.f, 0.f, 0.f};
            const i32x4* lrow = (const i32x4*)(htile + n * Hn);
#pragma unroll
            for (int kk = 0; kk < 32; kk += 4) {
                bf16x8 b0 = as_bf16x8(lrow[((kk + 0) * 4 + q) ^ swn]);
                bf16x8 b1 = as_bf16x8(lrow[((kk + 1) * 4 + q) ^ swn]);
                bf16x8 b2 = as_bf16x8(lrow[((kk + 2) * 4 + q) ^ swn]);
                bf16x8 b3 = as_bf16x8(lrow[((kk + 3) * 4 + q) ^ swn]);
                a0 = __builtin_amdgcn_mfma_f32_16x16x32_bf16(wfrag[kk + 0], b0, a0, 0, 0, 0);
                a1 = __builtin_amdgcn_mfma_f32_16x16x32_bf16(wfrag[kk + 1], b1, a1, 0, 0, 0);
                a2 = __builtin_amdgcn_mfma_f32_16x16x32_bf16(wfrag[kk + 2], b2, a2, 0, 0, 0);
                a3 = __builtin_amdgcn_mfma_f32_16x16x32_bf16(wfrag[kk + 3], b3, a3, 0, 0, 0);
            }
            a0 = a0 + a1;
            a2 = a2 + a3;
            a0 = a0 + a2;
        }

        // h_{t+1}[row0+n][colbase+4q+r] = tanh(a0[r]) — 4 contiguous cols.
        short s0 = f2bf(tanhf(a0[0]));
        short s1 = f2bf(tanhf(a0[1]));
        short s2 = f2bf(tanhf(a0[2]));
        short s3 = f2bf(tanhf(a0[3]));
        i32x2 pk;
        pk[0] = (s0 & 0xffff) | ((int)s1 << 16);
        pk[1] = (s2 & 0xffff) | ((int)s3 << 16);
        short* hdst = (((t + 1) & 1) ? h1 : h0) + (row0 + n) * Hn + colbase + 4 * q;
        asm volatile("global_store_dwordx2 %0, %1, off sc0 sc1"
                     :: "v"(hdst), "v"(pk) : "memory");
        asm volatile("s_waitcnt vmcnt(0)" ::: "memory");  // drain to MALL
        __syncthreads();  // all waves drained; also protects htile reuse
        if (tid == 0)
            __hip_atomic_store(&flags[i * 16 + j], t + 1, __ATOMIC_RELAXED,
                               __HIP_MEMORY_SCOPE_AGENT);
    }

    // ---- Epilogue: out = h_T @ W_ho + b_ho (h_T in buffer 0, Tn even) ----
    wait_group(myflags, lane, Tn);
    stage_h(h0, htile, row0, w, lane);
    __syncthreads();

    f32x4 acc = {0.f, 0.f, 0.f, 0.f};
    {
        const i32x4* lrow = (const i32x4*)(htile + n * Hn);
        const float* wcol = W_ho + (w * 256 + q * 8) * On + j * 16 + n;
#pragma unroll
        for (int kk = 0; kk < 8; ++kk) {
            bf16x8 af = as_bf16x8(lrow[(w * 32 + kk * 4 + q) ^ swn]);
            bf16x8 bf_;
#pragma unroll
            for (int e = 0; e < 8; ++e)
                bf_[e] = f2bf(wcol[(kk * 32 + e) * On]);
            acc = __builtin_amdgcn_mfma_f32_16x16x32_bf16(af, bf_, acc, 0, 0, 0);
        }
    }
#pragma unroll
    for (int r = 0; r < 4; ++r)
        red[w][q * 4 + r][n] = acc[r];
    __syncthreads();

    {
        int r = tid >> 4, c = tid & 15;
        float s = red[0][r][c] + red[1][r][c] + red[2][r][c] + red[3][r][c]
                + b_ho[j * 16 + c];
        out[(row0 + r) * On + j * 16 + c] = s;
    }
}

extern "C" void kernel_launch(void* const* d_in, const int* in_sizes, int n_in,
                              void* d_out, int out_size, void* d_ws, size_t ws_size,
                              hipStream_t stream) {
    const float* x    = (const float*)d_in[0];
    const float* W_ih = (const float*)d_in[1];
    const float* b_ih = (const float*)d_in[2];
    const float* W_ho = (const float*)d_in[3];
    const float* b_ho = (const float*)d_in[4];
    float* out = (float*)d_out;

    size_t need = (size_t)2 * Bsz * Hn * sizeof(short) + 16 * 16 * sizeof(int);
    if (ws_size < need) return;

    short* hbuf  = (short*)d_ws;
    int*   flags = (int*)((char*)d_ws + (size_t)2 * Bsz * Hn * sizeof(short));

    rnn_kernel<<<256, 256, 0, stream>>>(x, W_ih, b_ih, W_ho, b_ho, out,
                                        hbuf, flags);
}